// Round 2
// baseline (157.348 us; speedup 1.0000x reference)
//
#include <hip/hip_runtime.h>
#include <math.h>

#define PH 7
#define PW 7
#define B_ 4
#define C_ 256
#define H_ 50
#define W_ 50
#define R_ 256
#define S_ (H_ * W_)   // 2500
#define NCELL (PH * PW)  // 49

// Transpose features (B,C,H,W) -> (B,H,W,C) so channels are contiguous.
__global__ void transpose_chw_hwc(const float* __restrict__ in, float* __restrict__ out) {
    __shared__ float tile[32][33];  // +1 pad: no bank conflicts
    const int b  = blockIdx.z;
    const int s0 = blockIdx.x * 32;
    const int c0 = blockIdx.y * 32;
    const float* inb  = in  + (size_t)b * C_ * S_;
    float*       outb = out + (size_t)b * S_ * C_;
    const int tx = threadIdx.x;
    #pragma unroll
    for (int i = threadIdx.y; i < 32; i += 8) {
        const int s = s0 + tx;
        if (s < S_) tile[i][tx] = inb[(size_t)(c0 + i) * S_ + s];  // C_ multiple of 32
    }
    __syncthreads();
    #pragma unroll
    for (int i = threadIdx.y; i < 32; i += 8) {
        const int s = s0 + i;
        if (s < S_) outb[(size_t)s * C_ + (c0 + tx)] = tile[tx][i];
    }
}

// One block per roi. 512 threads = 8 waves. Each wave handles cells
// (wave, wave+8, ...); its 64 lanes cover all 256 channels via float4.
// Results staged in LDS in output order, then flushed coalesced: the whole
// 49 KB out region of roi r is written by this one block -> full-line
// HBM write-back (fixes the 10x write amplification seen in round 1).
__global__ void __launch_bounds__(512, 1)
roi_pool_block(const float* __restrict__ ft, const int* __restrict__ rois,
               float* __restrict__ out) {
    __shared__ float obuf[C_ * NCELL];  // 12544 floats = 49 KB

    const int r    = blockIdx.x;
    const int t    = threadIdx.x;        // 0..511
    const int wave = t >> 6;             // 0..7
    const int lane = t & 63;             // 0..63

    const int* roi = rois + r * 5;
    const int b  = roi[0];
    const int x1 = roi[1] >> 4;   // floor(v/16), v >= 0
    const int y1 = roi[2] >> 4;
    const int x2 = roi[3] >> 4;
    const int y2 = roi[4] >> 4;
    const int h = y2 - y1 + 1;
    const int w = x2 - x1 + 1;

    const float* fb = ft + (size_t)b * S_ * C_ + 4 * lane;

    for (int cell = wave; cell < NCELL; cell += 8) {
        const int ph = cell / PW;
        const int pw = cell % PW;
        const int sh = y1 + (ph * h) / PH;
        const int eh = y1 + ((ph + 1) * h + PH - 1) / PH;
        const int sw = x1 + (pw * w) / PW;
        const int ew = x1 + ((pw + 1) * w + PW - 1) / PW;

        float4 acc = make_float4(-INFINITY, -INFINITY, -INFINITY, -INFINITY);
        for (int y = sh; y < eh; ++y) {
            const float* rowp = fb + (size_t)(y * W_) * C_;
            for (int x = sw; x < ew; ++x) {
                const float4 v = *(const float4*)(rowp + (size_t)x * C_);
                acc.x = fmaxf(acc.x, v.x);
                acc.y = fmaxf(acc.y, v.y);
                acc.z = fmaxf(acc.z, v.z);
                acc.w = fmaxf(acc.w, v.w);
            }
        }
        const int c = 4 * lane;
        obuf[(c + 0) * NCELL + cell] = acc.x;
        obuf[(c + 1) * NCELL + cell] = acc.y;
        obuf[(c + 2) * NCELL + cell] = acc.z;
        obuf[(c + 3) * NCELL + cell] = acc.w;
    }

    __syncthreads();

    // Coalesced flush: 12544 floats = 3136 float4 per roi, contiguous.
    const float4* src = (const float4*)obuf;
    float4* dst = (float4*)(out + (size_t)r * C_ * NCELL);
    #pragma unroll
    for (int i = t; i < C_ * NCELL / 4; i += 512) {
        dst[i] = src[i];
    }
}

extern "C" void kernel_launch(void* const* d_in, const int* in_sizes, int n_in,
                              void* d_out, int out_size, void* d_ws, size_t ws_size,
                              hipStream_t stream) {
    const float* features = (const float*)d_in[0];
    const int*   rois     = (const int*)d_in[1];
    float*       out      = (float*)d_out;

    float* ft = (float*)d_ws;  // 10.24 MB, ws is preallocated scratch
    dim3 tgrid((S_ + 31) / 32, C_ / 32, B_);
    transpose_chw_hwc<<<tgrid, dim3(32, 8), 0, stream>>>(features, ft);
    roi_pool_block<<<R_, 512, 0, stream>>>(ft, rois, out);
}

// Round 3
// 99.711 us; speedup vs baseline: 1.5780x; 1.5780x over previous
//
#include <hip/hip_runtime.h>
#include <math.h>

#define PH 7
#define PW 7
#define B_ 4
#define C_ 256
#define H_ 50
#define W_ 50
#define R_ 256
#define S_ (H_ * W_)     // 2500
#define NCELL (PH * PW)  // 49
#define MAXW 9           // max window width: ceil(50/7)+1
#define NGRP 4           // cell groups per roi

// Transpose features (B,C,H,W) -> (B,H,W,C) so channels are contiguous.
__global__ void transpose_chw_hwc(const float* __restrict__ in, float* __restrict__ out) {
    __shared__ float tile[32][33];
    const int b  = blockIdx.z;
    const int s0 = blockIdx.x * 32;
    const int c0 = blockIdx.y * 32;
    const float* inb  = in  + (size_t)b * C_ * S_;
    float*       outb = out + (size_t)b * S_ * C_;
    const int tx = threadIdx.x;
    #pragma unroll
    for (int i = threadIdx.y; i < 32; i += 8) {
        const int s = s0 + tx;
        if (s < S_) tile[i][tx] = inb[(size_t)(c0 + i) * S_ + s];
    }
    __syncthreads();
    #pragma unroll
    for (int i = threadIdx.y; i < 32; i += 8) {
        const int s = s0 + i;
        if (s < S_) outb[(size_t)s * C_ + (c0 + tx)] = tile[tx][i];
    }
}

__device__ __forceinline__ float4 max4(float4 a, float4 b) {
    a.x = fmaxf(a.x, b.x); a.y = fmaxf(a.y, b.y);
    a.z = fmaxf(a.z, b.z); a.w = fmaxf(a.w, b.w);
    return a;
}

template <int NL>
__device__ __forceinline__ void flush(const float* __restrict__ obuf,
                                      float* __restrict__ dst, int cs, int t) {
    // obuf layout: [local_cell][channel]; dst: out + r*C_*NCELL, layout [c][cell]
    #pragma unroll
    for (int f = t; f < NL * C_; f += 256) {
        const int c = f / NL;          // constant divisor -> magic mul
        const int j = f - c * NL;
        dst[c * NCELL + cs + j] = obuf[j * C_ + c];
    }
}

// Block = (roi, cell-group). 256 threads = 4 waves; each wave covers all 256
// channels (lane owns 4 via float4) and strides over the group's cells.
// Loads are batched 2 rows x 9 clamped float4s for ILP (clamped duplicates are
// harmless under max). Results staged in LDS, flushed as one contiguous span.
__global__ void __launch_bounds__(256, 4)
roi_pool_cells(const float* __restrict__ ft, const int* __restrict__ rois,
               float* __restrict__ out) {
    __shared__ float obuf[13 * C_];  // up to 13 local cells x 256 ch = 13.3 KB

    const int r  = blockIdx.x;
    const int g  = blockIdx.y;
    const int cs = (g * NCELL) / NGRP;
    const int ce = ((g + 1) * NCELL) / NGRP;
    const int nl = ce - cs;          // 12 or 13

    const int t    = threadIdx.x;
    const int wave = t >> 6;
    const int lane = t & 63;

    const int* roi = rois + r * 5;
    const int b  = roi[0];
    const int x1 = roi[1] >> 4;   // floor(v/16), v >= 0
    const int y1 = roi[2] >> 4;
    const int x2 = roi[3] >> 4;
    const int y2 = roi[4] >> 4;
    const int h = y2 - y1 + 1;
    const int w = x2 - x1 + 1;

    const float* fb = ft + (size_t)b * S_ * C_ + 4 * lane;

    for (int j = wave; j < nl; j += 4) {
        const int cell = cs + j;
        const int ph = cell / PW;
        const int pw = cell % PW;
        const int sh = y1 + (ph * h) / PH;
        const int eh = y1 + ((ph + 1) * h + PH - 1) / PH;
        const int sw = x1 + (pw * w) / PW;
        const int ew = x1 + ((pw + 1) * w + PW - 1) / PW;
        const int n1 = ew - sw - 1;  // >= 0

        float4 acc = make_float4(-INFINITY, -INFINITY, -INFINITY, -INFINITY);
        for (int y = sh; y < eh; y += 2) {
            const int y2r = (y + 1 < eh) ? (y + 1) : y;  // dup-safe
            const int rb0 = y * W_ + sw;
            const int rb1 = y2r * W_ + sw;
            float4 v0[MAXW], v1[MAXW];
            #pragma unroll
            for (int k = 0; k < MAXW; ++k) {
                const int xo = (k < n1) ? k : n1;  // clamp: dup loads, max-safe
                v0[k] = *(const float4*)(fb + (size_t)(rb0 + xo) * C_);
                v1[k] = *(const float4*)(fb + (size_t)(rb1 + xo) * C_);
            }
            #pragma unroll
            for (int k = 0; k < MAXW; ++k) acc = max4(acc, max4(v0[k], v1[k]));
        }

        *(float4*)&obuf[j * C_ + 4 * lane] = acc;  // [cell][ch]: conflict-free
    }

    __syncthreads();

    float* dst = out + (size_t)r * C_ * NCELL;
    if (nl == 12) flush<12>(obuf, dst, cs, t);
    else          flush<13>(obuf, dst, cs, t);
}

extern "C" void kernel_launch(void* const* d_in, const int* in_sizes, int n_in,
                              void* d_out, int out_size, void* d_ws, size_t ws_size,
                              hipStream_t stream) {
    const float* features = (const float*)d_in[0];
    const int*   rois     = (const int*)d_in[1];
    float*       out      = (float*)d_out;

    float* ft = (float*)d_ws;  // 10.24 MB scratch
    dim3 tgrid((S_ + 31) / 32, C_ / 32, B_);
    transpose_chw_hwc<<<tgrid, dim3(32, 8), 0, stream>>>(features, ft);
    roi_pool_cells<<<dim3(R_, NGRP), 256, 0, stream>>>(ft, rois, out);
}

// Round 4
// 96.294 us; speedup vs baseline: 1.6340x; 1.0355x over previous
//
#include <hip/hip_runtime.h>
#include <math.h>

#define PH 7
#define PW 7
#define B_ 4
#define C_ 256
#define H_ 50
#define W_ 50
#define R_ 256
#define S_ (H_ * W_)     // 2500
#define NCELL (PH * PW)  // 49
#define MAXW 9           // max window width: ceil(50/7)+1
#define NGRP 4           // cell groups per roi

// Transpose features (B,C,H,W) -> (B,H,W,C) so channels are contiguous.
__global__ void transpose_chw_hwc(const float* __restrict__ in, float* __restrict__ out) {
    __shared__ float tile[32][33];
    const int b  = blockIdx.z;
    const int s0 = blockIdx.x * 32;
    const int c0 = blockIdx.y * 32;
    const float* inb  = in  + (size_t)b * C_ * S_;
    float*       outb = out + (size_t)b * S_ * C_;
    const int tx = threadIdx.x;
    #pragma unroll
    for (int i = threadIdx.y; i < 32; i += 8) {
        const int s = s0 + tx;
        if (s < S_) tile[i][tx] = inb[(size_t)(c0 + i) * S_ + s];
    }
    __syncthreads();
    #pragma unroll
    for (int i = threadIdx.y; i < 32; i += 8) {
        const int s = s0 + i;
        if (s < S_) outb[(size_t)s * C_ + (c0 + tx)] = tile[tx][i];
    }
}

__device__ __forceinline__ float4 max4(float4 a, float4 b) {
    a.x = fmaxf(a.x, b.x); a.y = fmaxf(a.y, b.y);
    a.z = fmaxf(a.z, b.z); a.w = fmaxf(a.w, b.w);
    return a;
}

template <int NL>
__device__ __forceinline__ void flush(const float* __restrict__ obuf,
                                      float* __restrict__ dst, int cs, int t) {
    // obuf layout: [local_cell][channel]; dst layout: [c][cell]
    #pragma unroll
    for (int f = t; f < NL * C_; f += 256) {
        const int c = f / NL;          // constant divisor -> magic mul
        const int j = f - c * NL;
        dst[c * NCELL + cs + j] = obuf[j * C_ + c];
    }
}

// Block = (roi, cell-group). 256 threads = 4 waves; each wave covers all 256
// channels (lane owns 4 via float4) and strides over the group's cells.
// Loads batched 2 rows x (exact width kw) float4s; the width test is
// wave-uniform (roi geometry is scalar per wave) so the guarded loads are
// cheap s_cbranch skips, not divergence. launch_bounds(256,2): 256-VGPR
// budget so the 72-VGPR load buffers cannot force scratch spills.
__global__ void __launch_bounds__(256, 2)
roi_pool_cells(const float* __restrict__ ft, const int* __restrict__ rois,
               float* __restrict__ out) {
    __shared__ float obuf[13 * C_];  // up to 13 local cells x 256 ch = 13.3 KB

    const int r  = blockIdx.x;
    const int g  = blockIdx.y;
    const int cs = (g * NCELL) / NGRP;
    const int ce = ((g + 1) * NCELL) / NGRP;
    const int nl = ce - cs;          // 12 or 13

    const int t    = threadIdx.x;
    const int wave = t >> 6;
    const int lane = t & 63;

    const int* roi = rois + r * 5;
    const int b  = roi[0];
    const int x1 = roi[1] >> 4;   // floor(v/16), v >= 0
    const int y1 = roi[2] >> 4;
    const int x2 = roi[3] >> 4;
    const int y2 = roi[4] >> 4;
    const int h = y2 - y1 + 1;
    const int w = x2 - x1 + 1;

    const float* fb = ft + (size_t)b * S_ * C_ + 4 * lane;

    for (int j = wave; j < nl; j += 4) {
        const int cell = cs + j;
        const int ph = cell / PW;
        const int pw = cell % PW;
        const int sh = y1 + (ph * h) / PH;
        const int eh = y1 + ((ph + 1) * h + PH - 1) / PH;
        const int sw = x1 + (pw * w) / PW;
        const int ew = x1 + ((pw + 1) * w + PW - 1) / PW;
        const int kw = ew - sw;      // 1..9, wave-uniform

        float4 acc = make_float4(-INFINITY, -INFINITY, -INFINITY, -INFINITY);
        for (int y = sh; y < eh; y += 2) {
            const int y2r = (y + 1 < eh) ? (y + 1) : y;  // dup row, max-safe
            const float* p0 = fb + (size_t)(y * W_ + sw) * C_;
            const float* p1 = fb + (size_t)(y2r * W_ + sw) * C_;
            float4 v0[MAXW], v1[MAXW];
            #pragma unroll
            for (int k = 0; k < MAXW; ++k) {
                if (k < kw) {                 // wave-uniform branch
                    v0[k] = *(const float4*)(p0 + (size_t)k * C_);
                    v1[k] = *(const float4*)(p1 + (size_t)k * C_);
                }
            }
            #pragma unroll
            for (int k = 0; k < MAXW; ++k) {
                if (k < kw) acc = max4(acc, max4(v0[k], v1[k]));
            }
        }

        *(float4*)&obuf[j * C_ + 4 * lane] = acc;  // [cell][ch]: conflict-free
    }

    __syncthreads();

    float* dst = out + (size_t)r * C_ * NCELL;
    if (nl == 12) flush<12>(obuf, dst, cs, t);
    else          flush<13>(obuf, dst, cs, t);
}

extern "C" void kernel_launch(void* const* d_in, const int* in_sizes, int n_in,
                              void* d_out, int out_size, void* d_ws, size_t ws_size,
                              hipStream_t stream) {
    const float* features = (const float*)d_in[0];
    const int*   rois     = (const int*)d_in[1];
    float*       out      = (float*)d_out;

    float* ft = (float*)d_ws;  // 10.24 MB scratch
    dim3 tgrid((S_ + 31) / 32, C_ / 32, B_);
    transpose_chw_hwc<<<tgrid, dim3(32, 8), 0, stream>>>(features, ft);
    roi_pool_cells<<<dim3(R_, NGRP), 256, 0, stream>>>(ft, rois, out);
}

// Round 5
// 92.829 us; speedup vs baseline: 1.6950x; 1.0373x over previous
//
#include <hip/hip_runtime.h>
#include <math.h>

#define PH 7
#define PW 7
#define B_ 4
#define C_ 256
#define H_ 50
#define W_ 50
#define R_ 256
#define S_ (H_ * W_)     // 2500
#define NCELL (PH * PW)  // 49
#define MAXW 9           // max window width: ceil(50/7)+1

// Transpose features (B,C,H,W) -> (B,H,W,C) so channels are contiguous.
__global__ void transpose_chw_hwc(const float* __restrict__ in, float* __restrict__ out) {
    __shared__ float tile[32][33];
    const int b  = blockIdx.z;
    const int s0 = blockIdx.x * 32;
    const int c0 = blockIdx.y * 32;
    const float* inb  = in  + (size_t)b * C_ * S_;
    float*       outb = out + (size_t)b * S_ * C_;
    const int tx = threadIdx.x;
    #pragma unroll
    for (int i = threadIdx.y; i < 32; i += 8) {
        const int s = s0 + tx;
        if (s < S_) tile[i][tx] = inb[(size_t)(c0 + i) * S_ + s];
    }
    __syncthreads();
    #pragma unroll
    for (int i = threadIdx.y; i < 32; i += 8) {
        const int s = s0 + i;
        if (s < S_) outb[(size_t)s * C_ + (c0 + tx)] = tile[tx][i];
    }
}

__device__ __forceinline__ float4 max4(float4 a, float4 b) {
    a.x = fmaxf(a.x, b.x); a.y = fmaxf(a.y, b.y);
    a.z = fmaxf(a.z, b.z); a.w = fmaxf(a.w, b.w);
    return a;
}

// One block (1 wave) per (cell, roi): bx = cell*256 + r. 12544 blocks = 49
// per CU -> max TLP + perfect balance (worst block = one 9x9 window).
// XCD swizzle: bx % 8 == r % 8, so all 49 cells of roi r dispatch to ONE
// XCD; their stride-196B partial-line stores assemble in that XCD's L2 and
// write back as full lines (this killed the 10x WRITE amplification that
// sank the round-1 version of this shape).
// Loads: lane owns 4 channels (float4, 1 KiB/wave, coalesced); 2 rows x kw
// guarded float4 batches in flight (wave-uniform branch, no divergence).
__global__ void __launch_bounds__(64, 4)
roi_pool_cell(const float* __restrict__ ft, const int* __restrict__ rois,
              float* __restrict__ out) {
    const int bx   = blockIdx.x;
    const int cell = bx >> 8;        // 0..48
    const int r    = bx & 255;       // 0..255
    const int lane = threadIdx.x;    // 0..63

    const int* roi = rois + r * 5;
    const int b  = roi[0];
    const int x1 = roi[1] >> 4;   // floor(v/16), v >= 0
    const int y1 = roi[2] >> 4;
    const int x2 = roi[3] >> 4;
    const int y2 = roi[4] >> 4;
    const int h = y2 - y1 + 1;
    const int w = x2 - x1 + 1;

    const int ph = cell / PW;
    const int pw = cell - ph * PW;
    const int sh = y1 + (ph * h) / PH;
    const int eh = y1 + ((ph + 1) * h + PH - 1) / PH;
    const int sw = x1 + (pw * w) / PW;
    const int ew = x1 + ((pw + 1) * w + PW - 1) / PW;
    const int kw = ew - sw;          // 1..9, wave-uniform

    const float* fb = ft + (size_t)b * S_ * C_ + 4 * lane;

    float4 acc = make_float4(-INFINITY, -INFINITY, -INFINITY, -INFINITY);
    for (int y = sh; y < eh; y += 2) {
        const int yb = (y + 1 < eh) ? (y + 1) : y;   // dup row, max-safe
        const float* p0 = fb + (size_t)(y  * W_ + sw) * C_;
        const float* p1 = fb + (size_t)(yb * W_ + sw) * C_;
        float4 v0[MAXW], v1[MAXW];
        #pragma unroll
        for (int k = 0; k < MAXW; ++k) {
            if (k < kw) {                            // wave-uniform branch
                v0[k] = *(const float4*)(p0 + (size_t)k * C_);
                v1[k] = *(const float4*)(p1 + (size_t)k * C_);
            }
        }
        #pragma unroll
        for (int k = 0; k < MAXW; ++k) {
            if (k < kw) acc = max4(acc, max4(v0[k], v1[k]));
        }
    }

    float* dst = out + ((size_t)r * C_ + 4 * lane) * NCELL + cell;
    dst[0]         = acc.x;
    dst[NCELL]     = acc.y;
    dst[2 * NCELL] = acc.z;
    dst[3 * NCELL] = acc.w;
}

extern "C" void kernel_launch(void* const* d_in, const int* in_sizes, int n_in,
                              void* d_out, int out_size, void* d_ws, size_t ws_size,
                              hipStream_t stream) {
    const float* features = (const float*)d_in[0];
    const int*   rois     = (const int*)d_in[1];
    float*       out      = (float*)d_out;

    float* ft = (float*)d_ws;  // 10.24 MB scratch
    dim3 tgrid((S_ + 31) / 32, C_ / 32, B_);
    transpose_chw_hwc<<<tgrid, dim3(32, 8), 0, stream>>>(features, ft);
    roi_pool_cell<<<NCELL * R_, 64, 0, stream>>>(ft, rois, out);
}

// Round 6
// 90.006 us; speedup vs baseline: 1.7482x; 1.0314x over previous
//
#include <hip/hip_runtime.h>
#include <math.h>

#define PH 7
#define PW 7
#define B_ 4
#define C_ 256
#define H_ 50
#define W_ 50
#define R_ 256
#define S_ (H_ * W_)     // 2500
#define NCELL (PH * PW)  // 49
#define MAXW 9           // max window width: ceil(50/7)+1

// ---------- kernel 1: features (B,C,H,W) -> (B,H,W,C) ----------
__global__ void transpose_chw_hwc(const float* __restrict__ in, float* __restrict__ out) {
    __shared__ float tile[32][33];
    const int b  = blockIdx.z;
    const int s0 = blockIdx.x * 32;
    const int c0 = blockIdx.y * 32;
    const float* inb  = in  + (size_t)b * C_ * S_;
    float*       outb = out + (size_t)b * S_ * C_;
    const int tx = threadIdx.x;
    #pragma unroll
    for (int i = threadIdx.y; i < 32; i += 8) {
        const int s = s0 + tx;
        if (s < S_) tile[i][tx] = inb[(size_t)(c0 + i) * S_ + s];
    }
    __syncthreads();
    #pragma unroll
    for (int i = threadIdx.y; i < 32; i += 8) {
        const int s = s0 + i;
        if (s < S_) outb[(size_t)s * C_ + (c0 + tx)] = tile[tx][i];
    }
}

__device__ __forceinline__ float4 max4(float4 a, float4 b) {
    a.x = fmaxf(a.x, b.x); a.y = fmaxf(a.y, b.y);
    a.z = fmaxf(a.z, b.z); a.w = fmaxf(a.w, b.w);
    return a;
}

// ---------- kernel 2: pool. One wave per (cell, roi). ----------
// Loads: lane owns 4 channels (float4, coalesced 1 KiB/point), 2 rows x kw
// guarded batches in flight. Stores: tmp[(r*49+cell)*256 + 4*lane] — each
// block writes ONE aligned contiguous 1 KiB span (16 full lines, shared with
// nobody) -> write amplification impossible, no XCD-mapping assumption.
__global__ void __launch_bounds__(64, 4)
roi_pool_cell(const float* __restrict__ ft, const int* __restrict__ rois,
              float* __restrict__ tmp) {
    const int bx   = blockIdx.x;
    const int cell = bx >> 8;        // 0..48
    const int r    = bx & 255;       // 0..255
    const int lane = threadIdx.x;    // 0..63

    const int* roi = rois + r * 5;
    const int b  = roi[0];
    const int x1 = roi[1] >> 4;   // floor(v/16), v >= 0
    const int y1 = roi[2] >> 4;
    const int x2 = roi[3] >> 4;
    const int y2 = roi[4] >> 4;
    const int h = y2 - y1 + 1;
    const int w = x2 - x1 + 1;

    const int ph = cell / PW;
    const int pw = cell - ph * PW;
    const int sh = y1 + (ph * h) / PH;
    const int eh = y1 + ((ph + 1) * h + PH - 1) / PH;
    const int sw = x1 + (pw * w) / PW;
    const int ew = x1 + ((pw + 1) * w + PW - 1) / PW;
    const int kw = ew - sw;          // 1..9, wave-uniform

    const float* fb = ft + (size_t)b * S_ * C_ + 4 * lane;

    float4 acc = make_float4(-INFINITY, -INFINITY, -INFINITY, -INFINITY);
    for (int y = sh; y < eh; y += 2) {
        const int yb = (y + 1 < eh) ? (y + 1) : y;   // dup row, max-safe
        const float* p0 = fb + (size_t)(y  * W_ + sw) * C_;
        const float* p1 = fb + (size_t)(yb * W_ + sw) * C_;
        float4 v0[MAXW], v1[MAXW];
        #pragma unroll
        for (int k = 0; k < MAXW; ++k) {
            if (k < kw) {                            // wave-uniform branch
                v0[k] = *(const float4*)(p0 + (size_t)k * C_);
                v1[k] = *(const float4*)(p1 + (size_t)k * C_);
            }
        }
        #pragma unroll
        for (int k = 0; k < MAXW; ++k) {
            if (k < kw) acc = max4(acc, max4(v0[k], v1[k]));
        }
    }

    *(float4*)(tmp + ((size_t)(r * NCELL + cell)) * C_ + 4 * lane) = acc;
}

// ---------- kernel 3: tmp (R,49,C) -> out (R,C,49), per-roi LDS tile ----------
// Padded stride 257 (257%32==1): conflict-free on both LDS phases.
// Both global phases fully coalesced.
__global__ void __launch_bounds__(256)
transpose_out(const float* __restrict__ tmp, float* __restrict__ out) {
    __shared__ float lds[NCELL * 257];  // 50.4 KB
    const int r = blockIdx.x;
    const int t = threadIdx.x;
    const float* src = tmp + (size_t)r * NCELL * C_;
    float*       dst = out + (size_t)r * C_ * NCELL;

    #pragma unroll
    for (int i = t; i < NCELL * C_; i += 256) {
        const int cell = i >> 8;         // i = cell*256 + c
        const int c    = i & 255;
        lds[cell * 257 + c] = src[i];
    }
    __syncthreads();
    #pragma unroll
    for (int f = t; f < NCELL * C_; f += 256) {
        const int c    = f / NCELL;      // const divisor -> magic mul
        const int cell = f - c * NCELL;  // f = c*49 + cell
        dst[f] = lds[cell * 257 + c];
    }
}

extern "C" void kernel_launch(void* const* d_in, const int* in_sizes, int n_in,
                              void* d_out, int out_size, void* d_ws, size_t ws_size,
                              hipStream_t stream) {
    const float* features = (const float*)d_in[0];
    const int*   rois     = (const int*)d_in[1];
    float*       out      = (float*)d_out;

    float* ft  = (float*)d_ws;                       // 10.24 MB
    float* tmp = ft + (size_t)B_ * S_ * C_;          // +12.85 MB (ws is 256 MB)

    dim3 tgrid((S_ + 31) / 32, C_ / 32, B_);
    transpose_chw_hwc<<<tgrid, dim3(32, 8), 0, stream>>>(features, ft);
    roi_pool_cell<<<NCELL * R_, 64, 0, stream>>>(ft, rois, tmp);
    transpose_out<<<R_, 256, 0, stream>>>(tmp, out);
}